// Round 22
// baseline (56.436 us; speedup 1.0000x reference)
//
#include <hip/hip_runtime.h>

// B=4096, S=512, D=2, H=4. ONE lane per chain; R22: 32 chains per wave,
// DUPLICATED across lane pairs (lane&31 = chain slot; lanes 32-63 compute
// redundantly, don't store) -> 2048 waves = 2/SIMD. Purpose: fill the ~3x
// latency-stall exposure measured at 1 wave/SIMD (R21: ~1400 cyc/ws vs
// ~450 issue). LDS halves to 17KB/block so 8 blocks/CU fit (136 < 160 KB).
// STEP macro (R18/R20/R21-verified packed v2f), NC=16 / W=16-17 geometry,
// depth-2 x prefetch, separate epilogue kernel: all byte-identical to R21.

#define NS 512

static constexpr long SP_OFF  = 4194304;   // sampler_probs
static constexpr long EO_OFF  = 8388608;   // estimator_out
static constexpr long LO_OFF  = 10485760;  // lstm_out
static constexpr long FID_OFF = 18874368;  // fid_adj

typedef float v2f __attribute__((ext_vector_type(2)));
#define PKF(a, b, c) __builtin_elementwise_fma((a), (b), (c))

// one full LSTM step; pair 0 = {j0,j1}, pair 1 = {j2,j3}. SLOT = LDS slot.
// (R18/R20/R21-verified macro; only the LDS write is predicated on stLane)
#define STEP(X0v_, X1v_, SLOT)                                                \
    {                                                                         \
        const v2f XA = {X0v_, X0v_};                                          \
        const v2f XB = {X1v_, X1v_};                                          \
        const v2f HB0 = {hh0, hh0}, HB1 = {hh1, hh1};                         \
        const v2f HB2 = {hh2, hh2}, HB3 = {hh3, hh3};                         \
        v2f aq[4][2];                                                         \
        _Pragma("unroll")                                                     \
        for (int g = 0; g < 4; ++g) {                                         \
            _Pragma("unroll")                                                 \
            for (int p = 0; p < 2; ++p) {                                     \
                v2f z = PKF(XA, wx0p[g][p], bthp[g][p]);                      \
                z = PKF(XB,  wx1p[g][p], z);                                  \
                z = PKF(HB0, whp[g][p][0], z);                                \
                z = PKF(HB1, whp[g][p][1], z);                                \
                z = PKF(HB2, whp[g][p][2], z);                                \
                z = PKF(HB3, whp[g][p][3], z);                                \
                aq[g][p] = z;                    /* revolutions */            \
            }                                                                 \
        }                                                                     \
        _Pragma("unroll")                                                     \
        for (int g = 0; g < 4; ++g) {                                         \
            const float c0 = __builtin_amdgcn_cosf(aq[g][0].x);               \
            const float c1 = __builtin_amdgcn_cosf(aq[g][0].y);               \
            const float c2 = __builtin_amdgcn_cosf(aq[g][1].x);               \
            const float c3 = __builtin_amdgcn_cosf(aq[g][1].y);               \
            const float p01 = c0 * c1, p23 = c2 * c3;                         \
            v2f q01, q23;                                                     \
            q01.x = c1 * p23;   /* out0 = c1c2c3   */                         \
            q01.y = p01;        /* out1 = c0c1     */                         \
            q23.x = p01 * c2;   /* out2 = c0c1c2   */                         \
            q23.y = p01 * p23;  /* out3 = c0c1c2c3 */                         \
            aq[g][0] = q01; aq[g][1] = q23;                                   \
        }                                                                     \
        v2f act[4][2];                                                        \
        _Pragma("unroll")                                                     \
        for (int g = 0; g < 4; ++g) {                                         \
            _Pragma("unroll")                                                 \
            for (int p = 0; p < 2; ++p) {                                     \
                const v2f y  = aq[g][p];                                      \
                const v2f y2 = y * y;                                         \
                v2f P = PKF(y2, AC7p[g], AC5p[g]);                            \
                P = PKF(y2, P, AC3p[g]);                                      \
                P = PKF(y2, P, AC1p[g]);                                      \
                act[g][p] = PKF(y, P, ACBp[g]);                               \
            }                                                                 \
        }                                                                     \
        _Pragma("unroll")                                                     \
        for (int p = 0; p < 2; ++p) {                                         \
            const v2f iu = act[0][p] * act[1][p];                             \
            cstp[p] = PKF(act[2][p], cstp[p], iu);                            \
            const v2f u2 = cstp[p] * cstp[p];                                 \
            const v2f nn = PKF(u2, u2 + K105, K945);                          \
            const v2f dd = PKF(u2, PKF(u2, K15, K420), K945);                 \
            const v2f oc = act[3][p] * cstp[p];                               \
            const v2f M  = oc * nn;                                           \
            hp[p].x = M.x * __builtin_amdgcn_rcpf(dd.x);                      \
            hp[p].y = M.y * __builtin_amdgcn_rcpf(dd.y);                      \
        }                                                                     \
        hh0 = hp[0].x; hh1 = hp[0].y; hh2 = hp[1].x; hh3 = hp[1].y;           \
        if (stLane) {                                                         \
            float4 hq; hq.x = hh0; hq.y = hh1; hq.z = hh2; hq.w = hh3;        \
            lw[SLOT] = hq;                                                    \
        }                                                                     \
    }

__global__ __launch_bounds__(64) void qlstm_kernel(
    const float* __restrict__ xin,
    const float* __restrict__ Wi, const float* __restrict__ bi,
    const float* __restrict__ Wu, const float* __restrict__ bu,
    const float* __restrict__ Wf, const float* __restrict__ bf,
    const float* __restrict__ Wo, const float* __restrict__ bo,
    const float* __restrict__ ti, const float* __restrict__ tu,
    const float* __restrict__ tf, const float* __restrict__ to_,
    float* __restrict__ out)
{
    const int lane = threadIdx.x;
    const int c    = lane & 31;            // chain slot (lanes 32-63 duplicate)
    const bool stLane = (lane < 32);
    const int w    = blockIdx.x;           // 0..2047, one wave per block
    const int k    = w & 15;               // chunk 0..15, uniform per wave
    const int wg2  = w >> 4;               // half-wave-group 0..127
    const long b   = (long)wg2 * 32 + c;   // this lane's chain

    // packed weights [gate][pair]; prescaled by 1/(2*pi); W row-major
    // (H=4 rows) x (D+H=6 cols): cols 0,1 = x; col 2+kk = h_kk.
    const float I2P = 0.15915494309189535f;
    v2f wx0p[4][2], wx1p[4][2], bthp[4][2], whp[4][2][4];
    {
        const float* Wg[4] = {Wi, Wu, Wf, Wo};
        const float* bg[4] = {bi, bu, bf, bo};
        const float* tg[4] = {ti, tu, tf, to_};
        #pragma unroll
        for (int g = 0; g < 4; ++g) {
            #pragma unroll
            for (int p = 0; p < 2; ++p) {
                const int j0 = 2*p, j1 = 2*p + 1;
                wx0p[g][p] = (v2f){Wg[g][j0*6+0]*I2P, Wg[g][j1*6+0]*I2P};
                wx1p[g][p] = (v2f){Wg[g][j0*6+1]*I2P, Wg[g][j1*6+1]*I2P};
                bthp[g][p] = (v2f){(bg[g][j0]+tg[g][j0])*I2P,
                                   (bg[g][j1]+tg[g][j1])*I2P};
                #pragma unroll
                for (int kk = 0; kk < 4; ++kk)
                    whp[g][p][kk] = (v2f){Wg[g][j0*6+2+kk]*I2P,
                                          Wg[g][j1*6+2+kk]*I2P};
            }
        }
    }

    // activation: sigma(q)=0.5+0.5*T(q/2) (coeffs folded), tanh(q)=T(q);
    // T = odd deg-7 poly. Gate order {i,u,f,o}: u is tanh, rest sigma.
    const v2f AC1p[4] = {{0.25f,0.25f}, {1.0f,1.0f}, {0.25f,0.25f}, {0.25f,0.25f}};
    const v2f AC3p[4] = {{-0.020833333f,-0.020833333f}, {-0.33333333f,-0.33333333f},
                         {-0.020833333f,-0.020833333f}, {-0.020833333f,-0.020833333f}};
    const v2f AC5p[4] = {{0.0019350f,0.0019350f}, {0.123842f,0.123842f},
                         {0.0019350f,0.0019350f}, {0.0019350f,0.0019350f}};
    const v2f AC7p[4] = {{-0.00011295f,-0.00011295f}, {-0.028914f,-0.028914f},
                         {-0.00011295f,-0.00011295f}, {-0.00011295f,-0.00011295f}};
    const v2f ACBp[4] = {{0.5f,0.5f}, {0.0f,0.0f}, {0.5f,0.5f}, {0.5f,0.5f}};
    const v2f K105 = {105.f,105.f}, K945 = {945.f,945.f};
    const v2f K15  = {15.f,15.f},   K420 = {420.f,420.f};

    // LDS staging: 2 buffers x 32 chains x 17 float4 (68-float chain stride)
    __shared__ float lds[2][32 * 68];

    const float4* xv = (const float4*)(xin + b * (NS * 2));
    const int oddk = k & 1;                 // (k=0 has oddk=0)
    const int t_c  = (k == 0) ? 0 : (31 * k - oddk);   // compute start (EVEN)
    int t4 = t_c >> 1;                      // float4 index
    const bool isC0 = (k == 0);

    float hh0 = 0.f, hh1 = 0.f, hh2 = 0.f, hh3 = 0.f;
    v2f cstp[2] = {{0.f,0.f},{0.f,0.f}};
    v2f hp[2];

    // depth-2 rolling x prefetch
    float4 xa = xv[t4];
    int tb = t4 + 1; if (tb > 255) tb = 255;
    float4 xb = xv[tb];

    // 3 batches: even k (and k=0): 16,16,15 (47 steps); odd k: 16,16,16 (48).
    // chunk0 stores all batches; k>0 stores batches 1,2 (odd k: batch1 from
    // slot 1 -- its slot 0 is the 17th warm step).
    #pragma unroll 1
    for (int s = 0; s < 3; ++s) {
        float4* lw = ((float4*)&lds[s & 1][0]) + c * 17;
        const int nph = (s < 2) ? 8 : (oddk ? 8 : 7);
        #pragma unroll 1
        for (int p = 0; p < nph; ++p) {
            int tn = t4 + 2; if (tn > 255) tn = 255;   // clamp (uniform)
            const float4 xc = xv[tn];
            STEP(xa.x, xa.y, 2 * p)
            STEP(xa.z, xa.w, 2 * p + 1)
            xa = xb; xb = xc; ++t4;
        }
        if (s == 2 && !oddk) {
            STEP(xa.x, xa.y, 14)           // tail half-step (t even)
        }
        if (isC0 || s >= 1) {
            asm volatile("s_waitcnt lgkmcnt(0)" ::: "memory");
            // slot q of batch s holds t = t_c + 16*s + q
            const int  fv  = (s == 1 && !isC0 && oddk) ? 1 : 0;
            const int  lim = (s == 2 && !oddk) ? 15 : 16;
            const long tbv = (long)t_c + 16 * s;
            const float4* lr = (const float4*)&lds[s & 1][0];
            // 32 chains x 16 slots = 512 float4 over 64 lanes: 8 iterations
            #pragma unroll
            for (int a = 0; a < 8; ++a) {
                const int idx = a * 64 + lane;
                const int ch = idx >> 4;           // 0..31
                const int q  = idx & 15;           // 0..15
                if (q >= fv && q < lim) {
                    const float4 v = lr[ch * 17 + q];
                    *(float4*)(out + LO_OFF +
                               (long)(wg2 * 32 + ch) * 2048 +
                               (tbv + q) * 4) = v;
                }
            }
        }
    }
}

// Elementwise pass over lstm_out: sampler logits/probs + estimator (+ fid).
// P0 = 1/2 + (cosTh*cos p0 - sinTh*sin p0*sin p1)/2 ; probs0 = sigmoid(2*P0-1)
__global__ __launch_bounds__(256) void epilogue_kernel(
    const float* __restrict__ sw, const float* __restrict__ ew,
    float* __restrict__ out)
{
    const long idx = (long)blockIdx.x * 256 + threadIdx.x;   // 0 .. B*S-1
    const float thsum = sw[0] + sw[1] + sw[2] + sw[3];
    const float K1 = __cosf(thsum), K2 = __sinf(thsum), Ke = __sinf(ew[0]);

    const float2 hp = *(const float2*)(out + LO_OFF + idx * 4); // h0, h1
    const float s0 = __sinf(hp.x), c0 = __cosf(hp.x), s1 = __sinf(hp.y);
    const float Dv = __builtin_fmaf(K1, c0, -(K2 * s0 * s1));   // 2*P0-1
    const float P0 = __builtin_fmaf(0.5f, Dv, 0.5f);
    const float sp0 = __builtin_amdgcn_rcpf(1.f + __expf(-Dv));

    float2 sl; sl.x = P0;  sl.y = 1.f - P0;
    float2 sp; sp.x = sp0; sp.y = 1.f - sp0;
    ((float2*)out)[idx] = sl;
    ((float2*)(out + SP_OFF))[idx] = sp;
    out[EO_OFF + idx] = Ke * s0;

    if (idx < 262144) {   // fid_adj: 512x512 complete graph minus diagonal
        const int rr = (int)idx >> 9, cc = (int)idx & 511;
        out[FID_OFF + idx] = (rr == cc) ? 0.f : 1.f;
    }
}

extern "C" void kernel_launch(void* const* d_in, const int* in_sizes, int n_in,
                              void* d_out, int out_size, void* d_ws, size_t ws_size,
                              hipStream_t stream) {
    (void)in_sizes; (void)n_in; (void)d_ws; (void)ws_size; (void)out_size;
    const float* xin = (const float*)d_in[0];
    const float* Wf  = (const float*)d_in[1];  const float* bf = (const float*)d_in[2];
    const float* Wi  = (const float*)d_in[3];  const float* bi = (const float*)d_in[4];
    const float* Wu  = (const float*)d_in[5];  const float* bu = (const float*)d_in[6];
    const float* Wo  = (const float*)d_in[7];  const float* bo = (const float*)d_in[8];
    const float* tf  = (const float*)d_in[9];  const float* ti = (const float*)d_in[10];
    const float* tu  = (const float*)d_in[11]; const float* to_ = (const float*)d_in[12];
    const float* sw  = (const float*)d_in[13]; const float* ew = (const float*)d_in[14];
    float* out = (float*)d_out;

    hipLaunchKernelGGL(qlstm_kernel, dim3(2048), dim3(64), 0, stream,
                       xin, Wi, bi, Wu, bu, Wf, bf, Wo, bo,
                       ti, tu, tf, to_, out);
    hipLaunchKernelGGL(epilogue_kernel, dim3(2097152/256), dim3(256), 0, stream, sw, ew, out);
}

// Round 23
// 43.322 us; speedup vs baseline: 1.3027x; 1.3027x over previous
//
#include <hip/hip_runtime.h>

// B=4096, S=512, D=2, H=4. ONE lane per chain, 64 chains per wave.
// R23 = R21 (PASS, 42.8us) with the phase loops FULLY UNROLLED and x loaded
// by direct per-phase constant index (no rolling xa/xb register copies).
// R21's '#pragma unroll 1' + register rotation forced an end-of-phase
// vmcnt(0) (copy needs the value) -> prefetch depth collapsed to 0 and the
// 64-scattered-line x load latency (~600-2000 cyc) was exposed every phase
// == the measured ~900 cyc/step issue-invariant, wave-invariant stall.
// Unrolled bodies let the scheduler hoist loads and rename registers.
// Geometry (NC=16, W=16/17), STEP macro, flush, epilogue: byte-identical
// to R21. 1024 waves = 1/SIMD.

#define NS 512

static constexpr long SP_OFF  = 4194304;   // sampler_probs
static constexpr long EO_OFF  = 8388608;   // estimator_out
static constexpr long LO_OFF  = 10485760;  // lstm_out
static constexpr long FID_OFF = 18874368;  // fid_adj

typedef float v2f __attribute__((ext_vector_type(2)));
#define PKF(a, b, c) __builtin_elementwise_fma((a), (b), (c))

// one full LSTM step; pair 0 = {j0,j1}, pair 1 = {j2,j3}. SLOT = LDS slot.
// (R18/R20/R21-verified macro, byte-identical)
#define STEP(X0v_, X1v_, SLOT)                                                \
    {                                                                         \
        const v2f XA = {X0v_, X0v_};                                          \
        const v2f XB = {X1v_, X1v_};                                          \
        const v2f HB0 = {hh0, hh0}, HB1 = {hh1, hh1};                         \
        const v2f HB2 = {hh2, hh2}, HB3 = {hh3, hh3};                         \
        v2f aq[4][2];                                                         \
        _Pragma("unroll")                                                     \
        for (int g = 0; g < 4; ++g) {                                         \
            _Pragma("unroll")                                                 \
            for (int p = 0; p < 2; ++p) {                                     \
                v2f z = PKF(XA, wx0p[g][p], bthp[g][p]);                      \
                z = PKF(XB,  wx1p[g][p], z);                                  \
                z = PKF(HB0, whp[g][p][0], z);                                \
                z = PKF(HB1, whp[g][p][1], z);                                \
                z = PKF(HB2, whp[g][p][2], z);                                \
                z = PKF(HB3, whp[g][p][3], z);                                \
                aq[g][p] = z;                    /* revolutions */            \
            }                                                                 \
        }                                                                     \
        _Pragma("unroll")                                                     \
        for (int g = 0; g < 4; ++g) {                                         \
            const float c0 = __builtin_amdgcn_cosf(aq[g][0].x);               \
            const float c1 = __builtin_amdgcn_cosf(aq[g][0].y);               \
            const float c2 = __builtin_amdgcn_cosf(aq[g][1].x);               \
            const float c3 = __builtin_amdgcn_cosf(aq[g][1].y);               \
            const float p01 = c0 * c1, p23 = c2 * c3;                         \
            v2f q01, q23;                                                     \
            q01.x = c1 * p23;   /* out0 = c1c2c3   */                         \
            q01.y = p01;        /* out1 = c0c1     */                         \
            q23.x = p01 * c2;   /* out2 = c0c1c2   */                         \
            q23.y = p01 * p23;  /* out3 = c0c1c2c3 */                         \
            aq[g][0] = q01; aq[g][1] = q23;                                   \
        }                                                                     \
        v2f act[4][2];                                                        \
        _Pragma("unroll")                                                     \
        for (int g = 0; g < 4; ++g) {                                         \
            _Pragma("unroll")                                                 \
            for (int p = 0; p < 2; ++p) {                                     \
                const v2f y  = aq[g][p];                                      \
                const v2f y2 = y * y;                                         \
                v2f P = PKF(y2, AC7p[g], AC5p[g]);                            \
                P = PKF(y2, P, AC3p[g]);                                      \
                P = PKF(y2, P, AC1p[g]);                                      \
                act[g][p] = PKF(y, P, ACBp[g]);                               \
            }                                                                 \
        }                                                                     \
        _Pragma("unroll")                                                     \
        for (int p = 0; p < 2; ++p) {                                         \
            const v2f iu = act[0][p] * act[1][p];                             \
            cstp[p] = PKF(act[2][p], cstp[p], iu);                            \
            const v2f u2 = cstp[p] * cstp[p];                                 \
            const v2f nn = PKF(u2, u2 + K105, K945);                          \
            const v2f dd = PKF(u2, PKF(u2, K15, K420), K945);                 \
            const v2f oc = act[3][p] * cstp[p];                               \
            const v2f M  = oc * nn;                                           \
            hp[p].x = M.x * __builtin_amdgcn_rcpf(dd.x);                      \
            hp[p].y = M.y * __builtin_amdgcn_rcpf(dd.y);                      \
        }                                                                     \
        hh0 = hp[0].x; hh1 = hp[0].y; hh2 = hp[1].x; hh3 = hp[1].y;           \
        float4 hq; hq.x = hh0; hq.y = hh1; hq.z = hh2; hq.w = hh3;            \
        lw[SLOT] = hq;                                                        \
    }

// one 2-step phase with direct-indexed x load (compile-time offset)
#define PHASE(PIDX, TIDX)                                                     \
    {                                                                         \
        const float4 xp = xv[(TIDX)];                                         \
        STEP(xp.x, xp.y, 2*(PIDX))                                            \
        STEP(xp.z, xp.w, 2*(PIDX)+1)                                          \
    }

// flush batch in LDS buffer BUF_: slot q holds t = TBV_ + q; store q in [FV_,LIM_)
#define FLUSH(BUF_, TBV_, FV_, LIM_)                                          \
    {                                                                         \
        asm volatile("s_waitcnt lgkmcnt(0)" ::: "memory");                    \
        const float4* lr = (const float4*)&lds[BUF_][0];                      \
        _Pragma("unroll")                                                     \
        for (int a = 0; a < 4; ++a) {                                         \
            const int ch = 16 * a + (lane >> 2);                              \
            _Pragma("unroll")                                                 \
            for (int g = 0; g < 4; ++g) {                                     \
                const int q = 4 * g + (lane & 3);                             \
                if (q >= (FV_) && q < (LIM_)) {                               \
                    const float4 v = lr[ch * 17 + q];                         \
                    *(float4*)(out + LO_OFF +                                 \
                               (long)(wgrp * 64 + ch) * 2048 +                \
                               ((long)(TBV_) + q) * 4) = v;                   \
                }                                                             \
            }                                                                 \
        }                                                                     \
    }

__global__ __launch_bounds__(64) void qlstm_kernel(
    const float* __restrict__ xin,
    const float* __restrict__ Wi, const float* __restrict__ bi,
    const float* __restrict__ Wu, const float* __restrict__ bu,
    const float* __restrict__ Wf, const float* __restrict__ bf,
    const float* __restrict__ Wo, const float* __restrict__ bo,
    const float* __restrict__ ti, const float* __restrict__ tu,
    const float* __restrict__ tf, const float* __restrict__ to_,
    float* __restrict__ out)
{
    const int lane = threadIdx.x;
    const int w    = blockIdx.x;           // 0..1023, one wave per block
    const int k    = w >> 6;               // chunk 0..15, uniform per wave
    const int wgrp = w & 63;
    const long b   = (long)wgrp * 64 + lane;   // this lane's chain

    // packed weights [gate][pair]; prescaled by 1/(2*pi); W row-major
    // (H=4 rows) x (D+H=6 cols): cols 0,1 = x; col 2+kk = h_kk.
    const float I2P = 0.15915494309189535f;
    v2f wx0p[4][2], wx1p[4][2], bthp[4][2], whp[4][2][4];
    {
        const float* Wg[4] = {Wi, Wu, Wf, Wo};
        const float* bg[4] = {bi, bu, bf, bo};
        const float* tg[4] = {ti, tu, tf, to_};
        #pragma unroll
        for (int g = 0; g < 4; ++g) {
            #pragma unroll
            for (int p = 0; p < 2; ++p) {
                const int j0 = 2*p, j1 = 2*p + 1;
                wx0p[g][p] = (v2f){Wg[g][j0*6+0]*I2P, Wg[g][j1*6+0]*I2P};
                wx1p[g][p] = (v2f){Wg[g][j0*6+1]*I2P, Wg[g][j1*6+1]*I2P};
                bthp[g][p] = (v2f){(bg[g][j0]+tg[g][j0])*I2P,
                                   (bg[g][j1]+tg[g][j1])*I2P};
                #pragma unroll
                for (int kk = 0; kk < 4; ++kk)
                    whp[g][p][kk] = (v2f){Wg[g][j0*6+2+kk]*I2P,
                                          Wg[g][j1*6+2+kk]*I2P};
            }
        }
    }

    // activation: sigma(q)=0.5+0.5*T(q/2) (coeffs folded), tanh(q)=T(q);
    // T = odd deg-7 poly. Gate order {i,u,f,o}: u is tanh, rest sigma.
    const v2f AC1p[4] = {{0.25f,0.25f}, {1.0f,1.0f}, {0.25f,0.25f}, {0.25f,0.25f}};
    const v2f AC3p[4] = {{-0.020833333f,-0.020833333f}, {-0.33333333f,-0.33333333f},
                         {-0.020833333f,-0.020833333f}, {-0.020833333f,-0.020833333f}};
    const v2f AC5p[4] = {{0.0019350f,0.0019350f}, {0.123842f,0.123842f},
                         {0.0019350f,0.0019350f}, {0.0019350f,0.0019350f}};
    const v2f AC7p[4] = {{-0.00011295f,-0.00011295f}, {-0.028914f,-0.028914f},
                         {-0.00011295f,-0.00011295f}, {-0.00011295f,-0.00011295f}};
    const v2f ACBp[4] = {{0.5f,0.5f}, {0.0f,0.0f}, {0.5f,0.5f}, {0.5f,0.5f}};
    const v2f K105 = {105.f,105.f}, K945 = {945.f,945.f};
    const v2f K15  = {15.f,15.f},   K420 = {420.f,420.f};

    // LDS staging: 2 buffers x 64 chains x 17 float4 (68-float chain stride)
    __shared__ float lds[2][64 * 68];

    const float4* xv = (const float4*)(xin + b * (NS * 2));
    const int oddk = k & 1;                 // (k=0 has oddk=0)
    const int t_c  = (k == 0) ? 0 : (31 * k - oddk);   // compute start (EVEN)
    const int t4_0 = t_c >> 1;              // base float4 index
    const bool isC0 = (k == 0);

    float hh0 = 0.f, hh1 = 0.f, hh2 = 0.f, hh3 = 0.f;
    v2f cstp[2] = {{0.f,0.f},{0.f,0.f}};
    v2f hp[2];

    // ---- batch 0: phases 0..7 (steps t_c .. t_c+15), LDS buffer 0 ----
    {
        float4* lw = ((float4*)&lds[0][0]) + lane * 17;
        #pragma unroll
        for (int p = 0; p < 8; ++p) PHASE(p, t4_0 + p)
        if (isC0) { FLUSH(0, t_c, 0, 16) }
    }
    // ---- batch 1: phases 0..7 (steps t_c+16 .. t_c+31), LDS buffer 1 ----
    {
        float4* lw = ((float4*)&lds[1][0]) + lane * 17;
        #pragma unroll
        for (int p = 0; p < 8; ++p) PHASE(p, t4_0 + 8 + p)
        const int fv1 = (!isC0 && oddk) ? 1 : 0;
        FLUSH(1, t_c + 16, fv1, 16)
    }
    // ---- batch 2: odd k: 8 phases (16 steps); even k: 7 phases + tail ----
    {
        float4* lw = ((float4*)&lds[0][0]) + lane * 17;
        if (oddk) {
            #pragma unroll
            for (int p = 0; p < 8; ++p) PHASE(p, t4_0 + 16 + p)
            FLUSH(0, t_c + 32, 0, 16)
        } else {
            #pragma unroll
            for (int p = 0; p < 7; ++p) PHASE(p, t4_0 + 16 + p)
            const float4 xp = xv[t4_0 + 23];
            STEP(xp.x, xp.y, 14)            // tail half-step (t even)
            FLUSH(0, t_c + 32, 0, 15)
        }
    }
}

// Elementwise pass over lstm_out: sampler logits/probs + estimator (+ fid).
// P0 = 1/2 + (cosTh*cos p0 - sinTh*sin p0*sin p1)/2 ; probs0 = sigmoid(2*P0-1)
__global__ __launch_bounds__(256) void epilogue_kernel(
    const float* __restrict__ sw, const float* __restrict__ ew,
    float* __restrict__ out)
{
    const long idx = (long)blockIdx.x * 256 + threadIdx.x;   // 0 .. B*S-1
    const float thsum = sw[0] + sw[1] + sw[2] + sw[3];
    const float K1 = __cosf(thsum), K2 = __sinf(thsum), Ke = __sinf(ew[0]);

    const float2 hp = *(const float2*)(out + LO_OFF + idx * 4); // h0, h1
    const float s0 = __sinf(hp.x), c0 = __cosf(hp.x), s1 = __sinf(hp.y);
    const float Dv = __builtin_fmaf(K1, c0, -(K2 * s0 * s1));   // 2*P0-1
    const float P0 = __builtin_fmaf(0.5f, Dv, 0.5f);
    const float sp0 = __builtin_amdgcn_rcpf(1.f + __expf(-Dv));

    float2 sl; sl.x = P0;  sl.y = 1.f - P0;
    float2 sp; sp.x = sp0; sp.y = 1.f - sp0;
    ((float2*)out)[idx] = sl;
    ((float2*)(out + SP_OFF))[idx] = sp;
    out[EO_OFF + idx] = Ke * s0;

    if (idx < 262144) {   // fid_adj: 512x512 complete graph minus diagonal
        const int rr = (int)idx >> 9, cc = (int)idx & 511;
        out[FID_OFF + idx] = (rr == cc) ? 0.f : 1.f;
    }
}

extern "C" void kernel_launch(void* const* d_in, const int* in_sizes, int n_in,
                              void* d_out, int out_size, void* d_ws, size_t ws_size,
                              hipStream_t stream) {
    (void)in_sizes; (void)n_in; (void)d_ws; (void)ws_size; (void)out_size;
    const float* xin = (const float*)d_in[0];
    const float* Wf  = (const float*)d_in[1];  const float* bf = (const float*)d_in[2];
    const float* Wi  = (const float*)d_in[3];  const float* bi = (const float*)d_in[4];
    const float* Wu  = (const float*)d_in[5];  const float* bu = (const float*)d_in[6];
    const float* Wo  = (const float*)d_in[7];  const float* bo = (const float*)d_in[8];
    const float* tf  = (const float*)d_in[9];  const float* ti = (const float*)d_in[10];
    const float* tu  = (const float*)d_in[11]; const float* to_ = (const float*)d_in[12];
    const float* sw  = (const float*)d_in[13]; const float* ew = (const float*)d_in[14];
    float* out = (float*)d_out;

    hipLaunchKernelGGL(qlstm_kernel, dim3(1024), dim3(64), 0, stream,
                       xin, Wi, bi, Wu, bu, Wf, bf, Wo, bo,
                       ti, tu, tf, to_, out);
    hipLaunchKernelGGL(epilogue_kernel, dim3(2097152/256), dim3(256), 0, stream, sw, ew, out);
}